// Round 5
// baseline (257.078 us; speedup 1.0000x reference)
//
#include <hip/hip_runtime.h>
#include <hip/hip_bf16.h>

// ---------------- problem constants (fixed by setup_inputs) ----------------
#define NUM_B   16
#define DIM     512
#define TT      1500
#define NROWS   (NUM_B * TT)              // 24000
#define NCODES  4096
#define ROW_TILES ((NROWS + 127) / 128)   // 188 (fallback path)
#define NROWS_PAD (ROW_TILES * 128)       // 24064
#define NSLICE  8                         // partial cd slices (atomic decontention)
#define SHIFTC  30.0f                     // exp shift: exp(SHIFT-d), cancels in softmax
#define NBLKX   (NCODES / 128)            // 32 col tiles (fallback path)
#define TBLKS   (NUM_B * 47)              // 752 transpose blocks (47 t-tiles of 32)
#define CBLKS   (NCODES / 4)              // 1024 cb blocks
#define NZERO   (NROWS_PAD + NSLICE * NCODES)   // Sg + cdp
#define NZERO2  (NZERO + 1)               // + tot scalar

// 256x256 gemm1 geometry
#define NTY2 (NROWS_PAD / 256)            // 94
#define NTX2 (NCODES / 256)               // 16
#define KTILES (DIM / 64)                 // 8

typedef __bf16 bf16x8 __attribute__((ext_vector_type(8)));
typedef float  floatx4 __attribute__((ext_vector_type(4)));
typedef unsigned short ushortx8 __attribute__((ext_vector_type(8)));

// async global->LDS, 16B per lane; dest = wave-uniform base + lane*16
__device__ __forceinline__ void glds16(const void* g, void* l) {
    __builtin_amdgcn_global_load_lds(
        (__attribute__((address_space(1))) void*)(void*)g,
        (__attribute__((address_space(3))) void*)l, 16, 0, 0);
}

// ---------------- prep: transpose + z2 (register-accum) + cb + ws zeroing -------
__global__ __launch_bounds__(256) void k_prep(
    const float* __restrict__ sf, const float* __restrict__ cb,
    unsigned short* __restrict__ zbf, unsigned short* __restrict__ cbbf,
    float* __restrict__ z2, float* __restrict__ c2, float* __restrict__ zero0,
    float* __restrict__ outp) {
    int id = blockIdx.x, tid = threadIdx.x;
    if (id < TBLKS) {
        __shared__ float tile[32][257];
        int b = id / 47, t0 = (id % 47) * 32;
        int tl = tid & 31, dg = tid >> 5;       // phase 1: t lane, d group (8x32)
        int tr = tid >> 3, dgr = tid & 7;       // phase 2: 8 lanes per t-row
        int tg = t0 + tr;
        float ssq = 0.f;
        unsigned short* dst = zbf + (size_t)(b * TT + tg) * DIM;
#pragma unroll
        for (int half = 0; half < 2; ++half) {
            int dbase = half * 256;
            if (half) __syncthreads();          // drain phase-2 reads of prev half
            int t = t0 + tl;
            if (t < TT) {
                const float* src = sf + (size_t)(b * DIM + dbase + dg * 32) * TT + t;
#pragma unroll
                for (int k = 0; k < 32; ++k)
                    tile[tl][dg * 32 + k] = src[(size_t)k * TT];
            }
            __syncthreads();
            if (tg < TT) {
#pragma unroll
                for (int seg = 0; seg < 4; ++seg) {
                    int d0 = seg * 64 + dgr * 8;
                    unsigned int h[8];
#pragma unroll
                    for (int i2 = 0; i2 < 8; ++i2) {
                        __hip_bfloat16 hb = __float2bfloat16(tile[tr][d0 + i2]);
                        h[i2] = __builtin_bit_cast(unsigned short, hb);
                        float vb = __bfloat162float(hb);
                        ssq += vb * vb;
                    }
                    uint4 o;
                    o.x = h[0] | (h[1] << 16); o.y = h[2] | (h[3] << 16);
                    o.z = h[4] | (h[5] << 16); o.w = h[6] | (h[7] << 16);
                    *(uint4*)(dst + dbase + d0) = o;
                }
            }
        }
        // reduce over the 8 lanes sharing tr (lane bits 0..2)
        ssq += __shfl_xor(ssq, 1); ssq += __shfl_xor(ssq, 2); ssq += __shfl_xor(ssq, 4);
        if (dgr == 0 && tg < TT) z2[b * TT + tg] = ssq;
    } else {
        int ci = id - TBLKS;
        int gid = ci * 256 + tid;
        if (gid < NZERO2) zero0[gid] = 0.f;
        if (ci == 0 && tid == 0) outp[0] = 1.0f;
        int k = ci * 4 + (tid >> 6);
        int lane = tid & 63;
        const float4* src = (const float4*)(cb + (size_t)k * DIM + lane * 8);
        float4 a = src[0], b2 = src[1];
        float vals[8] = {a.x, a.y, a.z, a.w, b2.x, b2.y, b2.z, b2.w};
        float s = 0.f;
        unsigned int h[8];
#pragma unroll
        for (int i = 0; i < 8; ++i) {
            __hip_bfloat16 hb = __float2bfloat16(vals[i]);
            h[i] = __builtin_bit_cast(unsigned short, hb);
            float vb = __bfloat162float(hb);
            s += vb * vb;
        }
        uint4 o;
        o.x = h[0] | (h[1] << 16); o.y = h[2] | (h[3] << 16);
        o.z = h[4] | (h[5] << 16); o.w = h[6] | (h[7] << 16);
        *(uint4*)(cbbf + (size_t)k * DIM + lane * 8) = o;
#pragma unroll
        for (int off = 32; off >= 1; off >>= 1) s += __shfl_down(s, off);
        if (lane == 0) c2[k] = s;
    }
}

// ---------------- pass 1: 256x256 4-phase/K-tile pipelined GEMM + exp -----------
// m201-faithful schedule, adapted to wave->half mapping. 8 waves: wr2=wave>>2
// selects A-half (128 rows), wc4=wave&3 selects 64 B-cols (wc4>>1 = B-half).
// Per K-tile t (buf = t&1):
//   q0: 12 ds_read (av0-3, bv01) | 2bar | MFMA rows0-3 x cols0-1
//   q1:  4 ds_read (bv23)        | 2bar | MFMA rows0-3 x cols2-3
//   q2:  8 ds_read (av4-7); stage B(t+2) (B last read q1 -> safe) | 2bar | MFMA
//   q3:  stage A(t+2) (A last read q2 -> safe); vmcnt(8) | 2bar | MFMA
// vmcnt(8) proof: outstanding at q3 wait = {B,A}(t+1)+{B,A}(t+2) = 16 loads;
// allow 8 -> oldest 8 (= all of tile t+1) complete, 2-tile prefetch retained.
// Never drained in the main loop. Prologue: stage tiles 0,1; vmcnt(8) = tile 0.
// Tail stages (t+2 >= KTILES) read mapped ws garbage into dead LDS regions to
// keep vmcnt counts uniform.

#define DSR(dst, addr) asm volatile("ds_read_b128 %0, %1" : "=v"(dst) : "v"(addr))
#define BARR() asm volatile("s_barrier" ::: "memory")
#define WAIT_LGKM() do { \
    asm volatile("s_waitcnt lgkmcnt(0)" ::: "memory"); \
    __builtin_amdgcn_sched_barrier(0); \
} while (0)
#define VMC8() asm volatile("s_waitcnt vmcnt(8)" ::: "memory")

#define STG_A(TT_, H_) do { \
    const unsigned short* _s = agp + (size_t)(H_) * 128 * DIM + (TT_) * 64; \
    unsigned short* _d = &As[(TT_) & 1][H_][0] + (wave << 9); \
    glds16(_s, _d); glds16(_s + (size_t)64 * DIM, _d + 4096); \
} while (0)
#define STG_B(TT_, H_) do { \
    const unsigned short* _s = bgp + (size_t)(H_) * 128 * DIM + (TT_) * 64; \
    unsigned short* _d = &Bs[(TT_) & 1][H_][0] + (wave << 9); \
    glds16(_s, _d); glds16(_s + (size_t)64 * DIM, _d + 4096); \
} while (0)

// 16 MFMA: row-frags IB..IB+3 x col-frags (via BV pair) over K=64 (2 k-slices)
#define MFMA16(IB, BV, JB) do { \
    __builtin_amdgcn_s_setprio(1); \
    _Pragma("unroll") \
    for (int ii = 0; ii < 4; ++ii) { \
        _Pragma("unroll") \
        for (int jj = 0; jj < 2; ++jj) { \
            floatx4 c_ = acc[(IB) + ii][(JB) + jj]; \
            c_ = __builtin_amdgcn_mfma_f32_16x16x32_bf16( \
                __builtin_bit_cast(bf16x8, BV[jj][0]), \
                __builtin_bit_cast(bf16x8, av[(IB) + ii][0]), c_, 0, 0, 0); \
            c_ = __builtin_amdgcn_mfma_f32_16x16x32_bf16( \
                __builtin_bit_cast(bf16x8, BV[jj][1]), \
                __builtin_bit_cast(bf16x8, av[(IB) + ii][1]), c_, 0, 0, 0); \
            acc[(IB) + ii][(JB) + jj] = c_; \
        } \
    } \
    __builtin_amdgcn_s_setprio(0); \
} while (0)

__global__ __launch_bounds__(512) void k_gemm1(
    const unsigned short* __restrict__ zbf, const unsigned short* __restrict__ cbbf,
    const float* __restrict__ z2, const float* __restrict__ c2,
    const int* __restrict__ lengths, const int* __restrict__ stride_p,
    float* __restrict__ Sg, unsigned short* __restrict__ Eg) {
    // LDS: [dbuf][half(128rows)][128x64 bf16] for A and B = 128 KiB
    __shared__ alignas(16) unsigned short As[2][2][8192];
    __shared__ alignas(16) unsigned short Bs[2][2][8192];
    __shared__ float z2s[256], c2s[256];
    __shared__ unsigned char vldp[256];
    __shared__ int s_any;

    int tid = threadIdx.x;
    int r0 = blockIdx.y * 256, c0 = blockIdx.x * 256;  // col-inner: A-panel reuse

    if (tid == 0) s_any = 0;
    __syncthreads();
    if (tid < 256) {
        int n = r0 + tid;
        int valid = 0;
        if (n < NROWS) {
            int b = n / TT, t_ = n - b * TT;
            int nv = lengths[b] / stride_p[0];
            if (nv > TT) nv = TT;
            valid = (t_ < nv);
        }
        if (valid) atomicOr(&s_any, 1);
        vldp[tid] = (unsigned char)valid;
        z2s[tid] = z2[r0 + tid];
        c2s[tid] = c2[c0 + tid];
    }
    __syncthreads();
    if (!s_any) return;   // fully-masked row tile: contributes nothing

    int wave = tid >> 6, lane = tid & 63;
    int l15 = lane & 15, l4 = lane >> 4;
    int wr2 = wave >> 2;          // A-half (128 rows)
    int wc4 = wave & 3;           // 64-col strip; B-half = wc4>>1

    // staging lane geometry (8 rows per glds16; source pre-swizzled:
    // chunk ^ (row&7) so linear-LDS ends up XOR-swizzled for reads)
    int srow8 = lane >> 3;
    int sg = (lane & 7) ^ srow8;
    const unsigned short* agp = zbf + (size_t)(r0 + wave * 8 + srow8) * DIM + sg * 8;
    const unsigned short* bgp = cbbf + (size_t)(c0 + wave * 8 + srow8) * DIM + sg * 8;

    // ds_read lane geometry
    unsigned AsB = (unsigned)(size_t)&As[0][0][0] + (unsigned)(wr2 * 16384);
    unsigned BsB = (unsigned)(size_t)&Bs[0][0][0] + (unsigned)((wc4 >> 1) * 16384);
    unsigned rowA = (unsigned)(l15 * 128);
    unsigned rowB = (unsigned)(((wc4 & 1) * 64 + l15) * 128);
    unsigned p0 = (unsigned)(((l4) ^ (l15 & 7)) * 16);
    unsigned p1 = (unsigned)(((4 + l4) ^ (l15 & 7)) * 16);

    floatx4 acc[8][4];
    const floatx4 zacc = {0.f, 0.f, 0.f, 0.f};
#pragma unroll
    for (int i = 0; i < 8; ++i)
#pragma unroll
        for (int j = 0; j < 4; ++j) acc[i][j] = zacc;

    // prologue: tiles 0 and 1 fully staged (16 loads); vmcnt(8) -> tile 0 landed
    STG_B(0, 0); STG_B(0, 1); STG_A(0, 0); STG_A(0, 1);
    STG_B(1, 0); STG_B(1, 1); STG_A(1, 0); STG_A(1, 1);
    VMC8();
    BARR();

    ushortx8 av[8][2];        // A fragments: [0..3] loaded q0, [4..7] q2
    ushortx8 bv01[2][2];      // B col-frags 0,1 (live q0->q2)
    ushortx8 bv23[2][2];      // B col-frags 2,3 (live q1->q3)

#pragma unroll
    for (int t = 0; t < KTILES; ++t) {
        unsigned dbase = (unsigned)((t & 1) * 32768);
        unsigned aA = AsB + dbase + rowA;
        unsigned aB = BsB + dbase + rowB;

        // ---- q0: read av0-3 (8) + bv01 (4)
        DSR(av[0][0], aA + p0); DSR(av[1][0], aA + 2048u + p0);
        DSR(av[2][0], aA + 4096u + p0); DSR(av[3][0], aA + 6144u + p0);
        DSR(av[0][1], aA + p1); DSR(av[1][1], aA + 2048u + p1);
        DSR(av[2][1], aA + 4096u + p1); DSR(av[3][1], aA + 6144u + p1);
        DSR(bv01[0][0], aB + p0); DSR(bv01[1][0], aB + 2048u + p0);
        DSR(bv01[0][1], aB + p1); DSR(bv01[1][1], aB + 2048u + p1);
        BARR(); WAIT_LGKM();
        MFMA16(0, bv01, 0);
        BARR();

        // ---- q1: read bv23 (4)
        DSR(bv23[0][0], aB + 4096u + p0); DSR(bv23[1][0], aB + 6144u + p0);
        DSR(bv23[0][1], aB + 4096u + p1); DSR(bv23[1][1], aB + 6144u + p1);
        BARR(); WAIT_LGKM();
        MFMA16(0, bv23, 2);
        BARR();

        // ---- q2: read av4-7 (8); stage B(t+2) (B-halves last read at q1)
        DSR(av[4][0], aA + 8192u + p0); DSR(av[5][0], aA + 10240u + p0);
        DSR(av[6][0], aA + 12288u + p0); DSR(av[7][0], aA + 14336u + p0);
        DSR(av[4][1], aA + 8192u + p1); DSR(av[5][1], aA + 10240u + p1);
        DSR(av[6][1], aA + 12288u + p1); DSR(av[7][1], aA + 14336u + p1);
        STG_B(t + 2, 0); STG_B(t + 2, 1);
        BARR(); WAIT_LGKM();
        MFMA16(4, bv01, 0);
        BARR();

        // ---- q3: stage A(t+2) (A-halves last read at q2); counted vmcnt
        STG_A(t + 2, 0); STG_A(t + 2, 1);
        VMC8();
        BARR();
        MFMA16(4, bv23, 2);
        BARR();
    }

    // epilogue: e = exp(SHIFT - sqrt(z2+c2-2*dot)); S += row-sum; E packed 8B
    // swapped-MFMA C/D: n = r0 + wr2*128 + i*16 + l15
    //                   k = c0 + wc4*64 + j*16 + l4*4 + reg
    float c2r[4][4];
#pragma unroll
    for (int j = 0; j < 4; ++j)
#pragma unroll
        for (int r = 0; r < 4; ++r)
            c2r[j][r] = c2s[wc4 * 64 + j * 16 + l4 * 4 + r];

#pragma unroll
    for (int i = 0; i < 8; ++i) {
        int rl = wr2 * 128 + i * 16 + l15;
        bool rv = vldp[rl] != 0;
        float z2v = z2s[rl];
        float s = 0.f;
        unsigned short* Ep = Eg + (size_t)(r0 + rl) * NCODES + c0 + wc4 * 64 + l4 * 4;
#pragma unroll
        for (int j = 0; j < 4; ++j) {
            float e[4];
#pragma unroll
            for (int r = 0; r < 4; ++r) {
                float d2 = z2v + c2r[j][r] - 2.0f * acc[i][j][r];
                float d = sqrtf(fmaxf(d2, 1e-12f));
                e[r] = __expf(SHIFTC - d);
                s += e[r];
            }
            if (rv) {
                unsigned h0 = __builtin_bit_cast(unsigned short, __float2bfloat16(e[0]));
                unsigned h1 = __builtin_bit_cast(unsigned short, __float2bfloat16(e[1]));
                unsigned h2 = __builtin_bit_cast(unsigned short, __float2bfloat16(e[2]));
                unsigned h3 = __builtin_bit_cast(unsigned short, __float2bfloat16(e[3]));
                uint2 o;
                o.x = h0 | (h1 << 16);
                o.y = h2 | (h3 << 16);
                *(uint2*)(Ep + 16 * j) = o;
            }
        }
        s += __shfl_xor(s, 16); s += __shfl_xor(s, 32);
        if (l4 == 0 && rv) atomicAdd(&Sg[r0 + rl], s);
    }
}

// ---------------- pass 2: memory-bound scan  cdp[slice][k] += E[n][k]/S[n] ------
__global__ __launch_bounds__(256) void k_scan(
    const unsigned short* __restrict__ Eg, const float* __restrict__ Sg,
    const int* __restrict__ lengths, const int* __restrict__ stride_p,
    float* __restrict__ cdp) {
    __shared__ float rs2[64];
    __shared__ unsigned char vrows[64];
    __shared__ int s_cnt;
    int tid = threadIdx.x;
    int r0 = blockIdx.y * 64;
    if (tid < 64) {                         // one wave: validity + compaction
        int valid = 0;
        float inv = 0.f;
        int n = r0 + tid;
        if (n < NROWS) {
            int b = n / TT, t = n - b * TT;
            int nv = lengths[b] / stride_p[0];
            if (nv > TT) nv = TT;
            valid = (t < nv);
            if (valid) inv = 1.0f / Sg[n];
        }
        unsigned long long mask = __ballot(valid);
        if (tid == 0) s_cnt = __popcll(mask);
        if (valid) {
            int pos = __popcll(mask & ((1ull << tid) - 1ull));
            vrows[pos] = (unsigned char)tid;
            rs2[pos] = inv;
        }
    }
    __syncthreads();
    int m = s_cnt;
    if (m == 0) return;

    int col0 = blockIdx.x * 2048 + tid * 8;
    const unsigned short* base = Eg + (size_t)r0 * NCODES + col0;
    float acc[8] = {0.f, 0.f, 0.f, 0.f, 0.f, 0.f, 0.f, 0.f};

#define ACC8(V, RN) do { \
    unsigned int _u[4] = {(V).x, (V).y, (V).z, (V).w}; \
    _Pragma("unroll") \
    for (int q = 0; q < 4; ++q) { \
        acc[2 * q]     += (RN) * __builtin_bit_cast(float, _u[q] << 16); \
        acc[2 * q + 1] += (RN) * __builtin_bit_cast(float, _u[q] & 0xffff0000u); \
    } \
} while (0)

    int i = 0;
    for (; i + 8 <= m; i += 8) {
        uint4 v0 = *(const uint4*)(base + (size_t)vrows[i]     * NCODES);
        uint4 v1 = *(const uint4*)(base + (size_t)vrows[i + 1] * NCODES);
        uint4 v2 = *(const uint4*)(base + (size_t)vrows[i + 2] * NCODES);
        uint4 v3 = *(const uint4*)(base + (size_t)vrows[i + 3] * NCODES);
        uint4 v4 = *(const uint4*)(base + (size_t)vrows[i + 4] * NCODES);
        uint4 v5 = *(const uint4*)(base + (size_t)vrows[i + 5] * NCODES);
        uint4 v6 = *(const uint4*)(base + (size_t)vrows[i + 6] * NCODES);
        uint4 v7 = *(const uint4*)(base + (size_t)vrows[i + 7] * NCODES);
        ACC8(v0, rs2[i]);     ACC8(v1, rs2[i + 1]);
        ACC8(v2, rs2[i + 2]); ACC8(v3, rs2[i + 3]);
        ACC8(v4, rs2[i + 4]); ACC8(v5, rs2[i + 5]);
        ACC8(v6, rs2[i + 6]); ACC8(v7, rs2[i + 7]);
    }
    for (; i < m; ++i) {
        uint4 v = *(const uint4*)(base + (size_t)vrows[i] * NCODES);
        ACC8(v, rs2[i]);
    }
#undef ACC8

    float* outp = cdp + (size_t)(blockIdx.y & (NSLICE - 1)) * NCODES;
#pragma unroll
    for (int t = 0; t < 8; ++t) atomicAdd(&outp[col0 + t], acc[t]);
}

// ---------------- fallback (small ws): two-pass GEMM (writes cdp slice 0) -------
template <int PASS>
__global__ __launch_bounds__(256, 2) void k_gemm(
    const unsigned short* __restrict__ zbf, const unsigned short* __restrict__ cbbf,
    const float* __restrict__ z2, const float* __restrict__ c2,
    const int* __restrict__ lengths, const int* __restrict__ stride_p,
    float* __restrict__ Sg, float* __restrict__ cd) {
    __shared__ unsigned short Asf[128 * 64];
    __shared__ unsigned short Bsf[128 * 64];
    __shared__ float z2s[128], c2s[128], rs[128];
    __shared__ int s_any;
    int tid = threadIdx.x;
    int r0 = blockIdx.y * 128, c0 = blockIdx.x * 128;
    if (tid == 0) s_any = 0;
    __syncthreads();
    if (tid < 128) {
        int n = r0 + tid;
        int valid = 0;
        if (n < NROWS) {
            int b = n / TT, t = n - b * TT;
            int stride = stride_p[0];
            int nv = lengths[b] / stride;
            if (nv > TT) nv = TT;
            valid = (t < nv);
        }
        if (valid) atomicOr(&s_any, 1);
        z2s[tid] = z2[r0 + tid];
        c2s[tid] = c2[c0 + tid];
        if (PASS == 2) rs[tid] = valid ? (1.0f / Sg[r0 + tid]) : 0.0f;
    }
    __syncthreads();
    if (!s_any) return;

    int wave = tid >> 6, lane = tid & 63;
    int l15 = lane & 15, l4 = lane >> 4;
    int wr = (wave >> 1) * 64, wc = (wave & 1) * 64;
    int srow = lane >> 3;
    int scg = (lane & 7) ^ srow;
    const unsigned short* ag = zbf + (size_t)(r0 + wave * 32 + srow) * DIM + scg * 8;
    const unsigned short* bg = cbbf + (size_t)(c0 + wave * 32 + srow) * DIM + scg * 8;
    unsigned short* al = Asf + (wave * 32) * 64;
    unsigned short* bl = Bsf + (wave * 32) * 64;

    floatx4 acc[4][4];
    const floatx4 zero = {0.f, 0.f, 0.f, 0.f};
#pragma unroll
    for (int i = 0; i < 4; ++i)
#pragma unroll
        for (int j = 0; j < 4; ++j) acc[i][j] = zero;
    int sw = l15 & 7;
    for (int kc = 0; kc < 8; ++kc) {
#pragma unroll
        for (int q = 0; q < 4; ++q) {
            glds16(ag + (size_t)q * 8 * DIM + kc * 64, al + q * 8 * 64);
            glds16(bg + (size_t)q * 8 * DIM + kc * 64, bl + q * 8 * 64);
        }
        __syncthreads();
#pragma unroll
        for (int ks = 0; ks < 64; ks += 32) {
            int g = (ks >> 3) + l4;
            int pcg = g ^ sw;
            bf16x8 av[4], bvv[4];
#pragma unroll
            for (int i = 0; i < 4; ++i)
                av[i] = __builtin_bit_cast(bf16x8, *(const ushortx8*)&Asf[(wr + 16 * i + l15) * 64 + pcg * 8]);
#pragma unroll
            for (int j = 0; j < 4; ++j)
                bvv[j] = __builtin_bit_cast(bf16x8, *(const ushortx8*)&Bsf[(wc + 16 * j + l15) * 64 + pcg * 8]);
#pragma unroll
            for (int i = 0; i < 4; ++i)
#pragma unroll
                for (int j = 0; j < 4; ++j)
                    acc[i][j] = __builtin_amdgcn_mfma_f32_16x16x32_bf16(av[i], bvv[j], acc[i][j], 0, 0, 0);
        }
        __syncthreads();
    }
    if (PASS == 1) {
#pragma unroll
        for (int i = 0; i < 4; ++i) {
#pragma unroll
            for (int r = 0; r < 4; ++r) {
                int rl = wr + 16 * i + 4 * l4 + r;
                float z2v = z2s[rl];
                float s = 0.f;
#pragma unroll
                for (int j = 0; j < 4; ++j) {
                    int cl = wc + 16 * j + l15;
                    float d2 = z2v + c2s[cl] - 2.0f * acc[i][j][r];
                    float d = sqrtf(fmaxf(d2, 1e-12f));
                    s += __expf(SHIFTC - d);
                }
                s += __shfl_xor(s, 1); s += __shfl_xor(s, 2);
                s += __shfl_xor(s, 4); s += __shfl_xor(s, 8);
                if (l15 == 0) atomicAdd(&Sg[r0 + rl], s);
            }
        }
    } else {
#pragma unroll
        for (int j = 0; j < 4; ++j) {
            int cl = wc + 16 * j + l15;
            float c2v = c2s[cl];
            float cs = 0.f;
#pragma unroll
            for (int i = 0; i < 4; ++i) {
#pragma unroll
                for (int r = 0; r < 4; ++r) {
                    int rl = wr + 16 * i + 4 * l4 + r;
                    float d2 = z2s[rl] + c2v - 2.0f * acc[i][j][r];
                    float d = sqrtf(fmaxf(d2, 1e-12f));
                    cs += __expf(SHIFTC - d) * rs[rl];
                }
            }
            cs += __shfl_xor(cs, 16); cs += __shfl_xor(cs, 32);
            if (l4 == 0) atomicAdd(&cd[c0 + cl], cs);
        }
    }
}

// ---------------- finalize (2-stage, 16 blocks each) ----------------------------
__global__ __launch_bounds__(256) void k_red(float* __restrict__ cdp,
                                             float* __restrict__ tot) {
    int k = blockIdx.x * 256 + threadIdx.x;
    float v = 0.f;
#pragma unroll
    for (int s = 0; s < NSLICE; ++s) v += cdp[(size_t)s * NCODES + k];
    cdp[k] = v;
    float t = v;
#pragma unroll
    for (int off = 32; off >= 1; off >>= 1) t += __shfl_down(t, off);
    if ((threadIdx.x & 63) == 0) atomicAdd(tot, t);
}

__global__ __launch_bounds__(256) void k_ent(const float* __restrict__ cdp,
                                             const float* __restrict__ tot,
                                             float* __restrict__ out) {
    int k = blockIdx.x * 256 + threadIdx.x;
    float inv = 1.0f / (tot[0] + 1e-8f);
    float p = cdp[k] * inv;
    float e = p * __logf(p + 1e-8f);
#pragma unroll
    for (int off = 32; off >= 1; off >>= 1) e += __shfl_down(e, off);
    if ((threadIdx.x & 63) == 0)
        atomicAdd(out, e * (1.0f / __logf((float)NCODES)));
}

// ---------------- launcher ----------------
extern "C" void kernel_launch(void* const* d_in, const int* in_sizes, int n_in,
                              void* d_out, int out_size, void* d_ws, size_t ws_size,
                              hipStream_t stream) {
    const float* sf = (const float*)d_in[0];
    const float* cb = (const float*)d_in[1];
    const int* lengths = (const int*)d_in[2];
    const int* stride_p = (const int*)d_in[3];

    float* wsf = (float*)d_ws;
    float* Sg = wsf;                                     // NROWS_PAD
    float* cdp = Sg + NROWS_PAD;                         // NSLICE*NCODES
    float* tot = wsf + NZERO;                            // 1 scalar
    const size_t OFF_Z2 = NZERO2;
    const size_t OFF_C2 = OFF_Z2 + NROWS_PAD;
    const size_t OFF_ZB = (OFF_C2 + NCODES + 3) & ~(size_t)3;  // 16B-align bf16 region
    float* z2 = wsf + OFF_Z2;
    float* c2 = wsf + OFF_C2;
    unsigned short* zbf = (unsigned short*)(wsf + OFF_ZB);     // NROWS_PAD*DIM bf16
    unsigned short* cbbf = zbf + (size_t)NROWS_PAD * DIM;      // NCODES*DIM bf16
    unsigned short* Eg = cbbf + (size_t)NCODES * DIM;          // NROWS_PAD*NCODES bf16

    size_t need = OFF_ZB * 4
                + ((size_t)NROWS_PAD * DIM + (size_t)NCODES * DIM
                 + (size_t)NROWS_PAD * NCODES) * 2;

    k_prep<<<dim3(TBLKS + CBLKS), 256, 0, stream>>>(
        sf, cb, zbf, cbbf, z2, c2, Sg, (float*)d_out);
    if (ws_size >= need) {
        k_gemm1<<<dim3(NTX2, NTY2), 512, 0, stream>>>(
            zbf, cbbf, z2, c2, lengths, stride_p, Sg, Eg);
        k_scan<<<dim3(2, NROWS_PAD / 64), 256, 0, stream>>>(
            Eg, Sg, lengths, stride_p, cdp);
    } else {
        k_gemm<1><<<dim3(NBLKX, ROW_TILES), 256, 0, stream>>>(zbf, cbbf, z2, c2, lengths, stride_p, Sg, cdp);
        k_gemm<2><<<dim3(NBLKX, ROW_TILES), 256, 0, stream>>>(zbf, cbbf, z2, c2, lengths, stride_p, Sg, cdp);
    }
    k_red<<<dim3(NCODES / 256), 256, 0, stream>>>(cdp, tot);
    k_ent<<<dim3(NCODES / 256), 256, 0, stream>>>(cdp, tot, (float*)d_out);
}